// Round 1
// baseline (453.286 us; speedup 1.0000x reference)
//
#include <hip/hip_runtime.h>
#include <hip/hip_bf16.h>
#include <stdint.h>

#define NNODES 10000
#define NEDGES 160000
#define INCH 1024
#define HCH 1024
#define OUTCH 512
#define MPAD 10112           // 79 * 128
#define EPSV 1e-5f
#define NEG 0.1f

typedef unsigned short u16;
typedef __bf16 bf16x8 __attribute__((ext_vector_type(8)));
typedef float f32x4 __attribute__((ext_vector_type(4)));
typedef __attribute__((address_space(1))) unsigned int gu32;
typedef __attribute__((address_space(3))) unsigned int lu32;

#define GL16(g, l) __builtin_amdgcn_global_load_lds((const gu32*)(g), (lu32*)(l), 16, 0, 0)

__device__ __forceinline__ float bf2f(u16 u) {
    union { unsigned int i; float f; } v; v.i = ((unsigned int)u) << 16; return v.f;
}
__device__ __forceinline__ u16 f2bf(float f) {
    union { float f; unsigned int i; } v; v.f = f;
    unsigned int r = v.i + 0x7fffu + ((v.i >> 16) & 1u);
    return (u16)(r >> 16);
}

// ---------- GraphNorm ----------
__global__ void colsum_k(const float* __restrict__ x, float* __restrict__ colsum) {
    int c = blockIdx.x * 256 + threadIdx.x;              // 0..1023
    int r0 = blockIdx.y * 157;
    int r1 = min(r0 + 157, NNODES);
    float s = 0.f;
    for (int r = r0; r < r1; ++r) s += x[(size_t)r * INCH + c];
    atomicAdd(&colsum[c], s);
}

__global__ void colvar_k(const float* __restrict__ x, const float* __restrict__ colsum,
                         const float* __restrict__ gms, float* __restrict__ varsum) {
    int c = blockIdx.x * 256 + threadIdx.x;
    float mean = colsum[c] * (1.0f / NNODES);
    float sub = gms[c] * mean;
    int r0 = blockIdx.y * 157;
    int r1 = min(r0 + 157, NNODES);
    float s = 0.f;
    for (int r = r0; r < r1; ++r) { float d = x[(size_t)r * INCH + c] - sub; s += d * d; }
    atomicAdd(&varsum[c], s);
}

__global__ void norm_k(const float* __restrict__ x, const float* __restrict__ colsum,
                       const float* __restrict__ varsum, const float* __restrict__ gms,
                       const float* __restrict__ gw, const float* __restrict__ gb,
                       u16* __restrict__ xn) {
    int gid = blockIdx.x * 256 + threadIdx.x;
    int e = gid * 4;
    int c = e & (INCH - 1);
    float4 xv = *(const float4*)(x + e);
    float4 cs = *(const float4*)(colsum + c);
    float4 vs = *(const float4*)(varsum + c);
    float4 g4 = *(const float4*)(gms + c);
    float4 w4 = *(const float4*)(gw + c);
    float4 b4 = *(const float4*)(gb + c);
    const float invn = 1.0f / NNODES;
    ushort4 o;
    float m, sc, val;
    m = cs.x * invn; sc = rsqrtf(vs.x * invn + EPSV) * w4.x; val = (xv.x - g4.x * m) * sc + b4.x; o.x = f2bf(val);
    m = cs.y * invn; sc = rsqrtf(vs.y * invn + EPSV) * w4.y; val = (xv.y - g4.y * m) * sc + b4.y; o.y = f2bf(val);
    m = cs.z * invn; sc = rsqrtf(vs.z * invn + EPSV) * w4.z; val = (xv.z - g4.z * m) * sc + b4.z; o.z = f2bf(val);
    m = cs.w * invn; sc = rsqrtf(vs.w * invn + EPSV) * w4.w; val = (xv.w - g4.w * m) * sc + b4.w; o.w = f2bf(val);
    *(ushort4*)(xn + e) = o;
}

// ---------- weight convert (transpose to [col][k] bf16) ----------
__global__ void wt1_k(const float* __restrict__ W, u16* __restrict__ Bt) {
    int gid = blockIdx.x * 256 + threadIdx.x;   // 1M
    int ccol = gid >> 10;
    int k = gid & 1023;
    Bt[gid] = f2bf(W[(size_t)k * HCH + ccol]);
}
__global__ void wt2_k(const float* __restrict__ Wm, const float* __restrict__ Ws,
                      u16* __restrict__ Bt) {
    int gid = blockIdx.x * 256 + threadIdx.x;
    int ccol = gid >> 10;
    int k = gid & 1023;
    float v = (ccol < OUTCH) ? Wm[(size_t)k * OUTCH + ccol]
                             : Ws[(size_t)k * OUTCH + (ccol - OUTCH)];
    Bt[gid] = f2bf(v);
}

// ---------- CSR build ----------
__global__ void deg_k(const int* __restrict__ dst, int* __restrict__ cnt) {
    int e = blockIdx.x * 256 + threadIdx.x;
    if (e < NEDGES) atomicAdd(&cnt[dst[e]], 1);
}
__global__ void dis_k(const int* __restrict__ cnt, float* __restrict__ dis) {
    int i = blockIdx.x * 256 + threadIdx.x;
    if (i < NNODES) dis[i] = rsqrtf((float)(cnt[i] + 1));
}
__global__ void scan_k(const int* __restrict__ cnt, int* __restrict__ row_ptr,
                       int* __restrict__ cursor) {
    __shared__ int sm[256];
    int tid = threadIdx.x;
    const int per = 40;                 // 256*40 >= 10000
    int base = tid * per;
    int s = 0;
    for (int i = 0; i < per; ++i) { int idx = base + i; if (idx < NNODES) s += cnt[idx]; }
    sm[tid] = s; __syncthreads();
    for (int off = 1; off < 256; off <<= 1) {
        int v = (tid >= off) ? sm[tid - off] : 0;
        __syncthreads();
        sm[tid] += v;
        __syncthreads();
    }
    int run = (tid == 0) ? 0 : sm[tid - 1];
    for (int i = 0; i < per; ++i) {
        int idx = base + i;
        if (idx < NNODES) { row_ptr[idx] = run; cursor[idx] = run; run += cnt[idx]; }
    }
    if (tid == 255) row_ptr[NNODES] = sm[255];
}
__global__ void fill_k(const int* __restrict__ src, const int* __restrict__ dst,
                       const float* __restrict__ dis, int* __restrict__ cursor,
                       int* __restrict__ csr_src, float* __restrict__ csr_w) {
    int e = blockIdx.x * 256 + threadIdx.x;
    if (e >= NEDGES) return;
    int s = src[e], d = dst[e];
    int pos = atomicAdd(&cursor[d], 1);
    csr_src[pos] = s;
    csr_w[pos] = dis[s] * dis[d];
}

// ---------- aggregation: out[i] = sum_{e: dst=i} w_e * in[src_e] + (1/deg_i)*in[i] ----------
template<int MODE>   // MODE 1: +bias then leaky_relu
__global__ void agg_k(const u16* __restrict__ in, u16* __restrict__ out,
                      const int* __restrict__ row_ptr, const int* __restrict__ csr_src,
                      const float* __restrict__ csr_w, const float* __restrict__ dis,
                      const float* __restrict__ bias) {
    int node = blockIdx.x;
    int c = threadIdx.x * 4;
    float dv = dis[node];
    float selfw = dv * dv;
    ushort4 sv = *(const ushort4*)(in + (size_t)node * HCH + c);
    float a0 = bf2f(sv.x) * selfw, a1 = bf2f(sv.y) * selfw;
    float a2 = bf2f(sv.z) * selfw, a3 = bf2f(sv.w) * selfw;
    int e0 = row_ptr[node], e1 = row_ptr[node + 1];
    for (int e = e0; e < e1; ++e) {
        int s = csr_src[e];
        float w = csr_w[e];
        ushort4 v = *(const ushort4*)(in + (size_t)s * HCH + c);
        a0 += bf2f(v.x) * w; a1 += bf2f(v.y) * w;
        a2 += bf2f(v.z) * w; a3 += bf2f(v.w) * w;
    }
    if (MODE == 1) {
        float4 b = *(const float4*)(bias + c);
        a0 += b.x; a1 += b.y; a2 += b.z; a3 += b.w;
        a0 = a0 > 0.f ? a0 : NEG * a0;
        a1 = a1 > 0.f ? a1 : NEG * a1;
        a2 = a2 > 0.f ? a2 : NEG * a2;
        a3 = a3 > 0.f ? a3 : NEG * a3;
    }
    ushort4 o; o.x = f2bf(a0); o.y = f2bf(a1); o.z = f2bf(a2); o.w = f2bf(a3);
    *(ushort4*)(out + (size_t)node * HCH + c) = o;
}

// ---------- bf16 MFMA GEMM: C[MPAD x 1024] = A[MPAD x 1024] * Bt^T (Bt is [1024 cols][1024 k]) ----------
// EPI 0: store bf16 to Cbf.  EPI 1: +bias (bm cols 0..511, bs cols 512..1023), store fp32
//        z / mu / logstd slices of out with row<NNODES bound.
template<int EPI>
__global__ __launch_bounds__(256) void gemm_k(
    const u16* __restrict__ A, const u16* __restrict__ Bt,
    u16* __restrict__ Cbf, float* __restrict__ out,
    const float* __restrict__ bm, const float* __restrict__ bs) {
    __shared__ u16 As[128 * 32];
    __shared__ u16 Bs[128 * 32];
    const int tid = threadIdx.x;
    const int wave = tid >> 6;
    const int lane = tid & 63;
    const int row0 = blockIdx.y * 128;
    const int col0 = blockIdx.x * 128;
    const int wr = wave >> 1, wc = wave & 1;   // 2x2 wave grid, each wave 64x64
    const int sr = lane >> 2;                  // staging row in 16-row group
    const int sc = (lane & 3) * 8;             // staging col (elements)
    u16* AsW0 = &As[(wave * 16) * 32];
    u16* AsW1 = &As[(64 + wave * 16) * 32];
    u16* BsW0 = &Bs[(wave * 16) * 32];
    u16* BsW1 = &Bs[(64 + wave * 16) * 32];
    const u16* Ag0 = A + (size_t)(row0 + wave * 16 + sr) * 1024 + sc;
    const u16* Ag1 = A + (size_t)(row0 + 64 + wave * 16 + sr) * 1024 + sc;
    const u16* Bg0 = Bt + (size_t)(col0 + wave * 16 + sr) * 1024 + sc;
    const u16* Bg1 = Bt + (size_t)(col0 + 64 + wave * 16 + sr) * 1024 + sc;

    f32x4 acc[4][4] = {};
    const int arow = lane & 15;
    const int ak = (lane >> 4) * 8;
    for (int kk = 0; kk < 1024; kk += 32) {
        GL16(Ag0 + kk, AsW0);
        GL16(Ag1 + kk, AsW1);
        GL16(Bg0 + kk, BsW0);
        GL16(Bg1 + kk, BsW1);
        __syncthreads();
        bf16x8 af[4], bf[4];
#pragma unroll
        for (int m = 0; m < 4; ++m)
            af[m] = *reinterpret_cast<const bf16x8*>(&As[(wr * 64 + m * 16 + arow) * 32 + ak]);
#pragma unroll
        for (int n = 0; n < 4; ++n)
            bf[n] = *reinterpret_cast<const bf16x8*>(&Bs[(wc * 64 + n * 16 + arow) * 32 + ak]);
#pragma unroll
        for (int m = 0; m < 4; ++m)
#pragma unroll
            for (int n = 0; n < 4; ++n)
                acc[m][n] = __builtin_amdgcn_mfma_f32_16x16x32_bf16(af[m], bf[n], acc[m][n], 0, 0, 0);
        __syncthreads();
    }
    const int crow = (lane >> 4) * 4;
    const int ccol = lane & 15;
    if (EPI == 0) {
#pragma unroll
        for (int m = 0; m < 4; ++m) {
            int rbase = row0 + wr * 64 + m * 16 + crow;
#pragma unroll
            for (int n = 0; n < 4; ++n) {
                int col = col0 + wc * 64 + n * 16 + ccol;
                f32x4 v = acc[m][n];
#pragma unroll
                for (int r = 0; r < 4; ++r)
                    Cbf[(size_t)(rbase + r) * 1024 + col] = f2bf(v[r]);
            }
        }
    } else {
        const size_t NOUT = (size_t)NNODES * OUTCH;
#pragma unroll
        for (int n = 0; n < 4; ++n) {
            int col = col0 + wc * 64 + n * 16 + ccol;
            bool lo = col < OUTCH;
            int colo = lo ? col : col - OUTCH;
            float bias = lo ? bm[colo] : bs[colo];
#pragma unroll
            for (int m = 0; m < 4; ++m) {
                int rbase = row0 + wr * 64 + m * 16 + crow;
                f32x4 v = acc[m][n];
#pragma unroll
                for (int r = 0; r < 4; ++r) {
                    int rr = rbase + r;
                    if (rr < NNODES) {
                        float val = v[r] + bias;
                        if (lo) {
                            out[(size_t)rr * OUTCH + colo] = val;           // z
                            out[NOUT + (size_t)rr * OUTCH + colo] = val;    // mu
                        } else {
                            out[2 * NOUT + (size_t)rr * OUTCH + colo] = val; // logstd
                        }
                    }
                }
            }
        }
    }
}

extern "C" void kernel_launch(void* const* d_in, const int* in_sizes, int n_in,
                              void* d_out, int out_size, void* d_ws, size_t ws_size,
                              hipStream_t stream) {
    const float* x   = (const float*)d_in[0];
    const int*   ei  = (const int*)d_in[1];
    const float* W1  = (const float*)d_in[2];
    const float* b1  = (const float*)d_in[3];
    const float* Wm  = (const float*)d_in[4];
    const float* bm  = (const float*)d_in[5];
    const float* Ws  = (const float*)d_in[6];
    const float* bs  = (const float*)d_in[7];
    const float* gw  = (const float*)d_in[8];
    const float* gb  = (const float*)d_in[9];
    const float* gms = (const float*)d_in[10];
    const int* srcI = ei;
    const int* dstI = ei + NEDGES;

    char* ws = (char*)d_ws;
    const size_t SBIG = (size_t)MPAD * 1024 * 2;   // 20,709,376 bytes
    u16* xn   = (u16*)(ws);
    u16* h1g  = (u16*)(ws + SBIG);
    u16* h    = (u16*)(ws + 2 * SBIG);
    u16* aggh = xn;                                 // reuse (xn dead after gemm1)
    u16* Bt1  = (u16*)(ws + 3 * SBIG);
    u16* Bt2  = (u16*)(ws + 3 * SBIG + (size_t)2 * 1024 * 1024);
    char* small   = ws + 3 * SBIG + (size_t)4 * 1024 * 1024;
    float* colsum = (float*)(small);
    float* varsum = (float*)(small + 4096);
    int*   cnt    = (int*)(small + 8192);           // 40000 B
    int*   row_ptr= (int*)(small + 49152);          // 40004 B
    int*   cursor = (int*)(small + 49152 + 40960);
    float* dis    = (float*)(small + 49152 + 81920);
    int*   csr_src= (int*)(small + 49152 + 122880);
    float* csr_w  = (float*)(small + 49152 + 122880 + 640000);

    // zero colsum | varsum | cnt (contiguous 48192 B)
    hipMemsetAsync(small, 0, 48192, stream);

    colsum_k<<<dim3(4, 64), 256, 0, stream>>>(x, colsum);
    colvar_k<<<dim3(4, 64), 256, 0, stream>>>(x, colsum, gms, varsum);
    norm_k<<<10000, 256, 0, stream>>>(x, colsum, varsum, gms, gw, gb, xn);
    wt1_k<<<4096, 256, 0, stream>>>(W1, Bt1);
    wt2_k<<<4096, 256, 0, stream>>>(Wm, Ws, Bt2);
    deg_k<<<625, 256, 0, stream>>>(dstI, cnt);
    dis_k<<<40, 256, 0, stream>>>(cnt, dis);
    scan_k<<<1, 256, 0, stream>>>(cnt, row_ptr, cursor);
    fill_k<<<625, 256, 0, stream>>>(srcI, dstI, dis, cursor, csr_src, csr_w);

    gemm_k<0><<<dim3(8, 79), 256, 0, stream>>>(xn, Bt1, h1g, nullptr, nullptr, nullptr);
    agg_k<1><<<NNODES, 256, 0, stream>>>(h1g, h, row_ptr, csr_src, csr_w, dis, b1);
    agg_k<0><<<NNODES, 256, 0, stream>>>(h, aggh, row_ptr, csr_src, csr_w, dis, nullptr);
    gemm_k<1><<<dim3(8, 79), 256, 0, stream>>>(aggh, Bt2, nullptr, (float*)d_out, bm, bs);
}

// Round 2
// 415.096 us; speedup vs baseline: 1.0920x; 1.0920x over previous
//
#include <hip/hip_runtime.h>
#include <hip/hip_bf16.h>
#include <stdint.h>

#define NNODES 10000
#define NEDGES 160000
#define INCH 1024
#define HCH 1024
#define OUTCH 512
#define MPAD 10112           // 79 * 128
#define EPSV 1e-5f
#define NEG 0.1f

typedef unsigned short u16;
typedef __bf16 bf16x8 __attribute__((ext_vector_type(8)));
typedef float f32x4 __attribute__((ext_vector_type(4)));
typedef __attribute__((address_space(1))) unsigned int gu32;
typedef __attribute__((address_space(3))) unsigned int lu32;

#define GL16(g, l) __builtin_amdgcn_global_load_lds((const gu32*)(g), (lu32*)(l), 16, 0, 0)

__device__ __forceinline__ float bf2f(u16 u) {
    union { unsigned int i; float f; } v; v.i = ((unsigned int)u) << 16; return v.f;
}
__device__ __forceinline__ u16 f2bf(float f) {
    union { float f; unsigned int i; } v; v.f = f;
    unsigned int r = v.i + 0x7fffu + ((v.i >> 16) & 1u);
    return (u16)(r >> 16);
}

// ---------- GraphNorm pass 1: fused column sum + sum-of-squares ----------
// 625 blocks x 16 rows each; thread t owns columns 4t..4t+3 (float4).
__global__ __launch_bounds__(256) void sumsq_k(const float* __restrict__ x,
                                               float* __restrict__ colsum,
                                               float* __restrict__ colsq) {
    int c = threadIdx.x * 4;
    int r0 = blockIdx.x * 16;
    float s0 = 0.f, s1 = 0.f, s2 = 0.f, s3 = 0.f;
    float q0 = 0.f, q1 = 0.f, q2 = 0.f, q3 = 0.f;
#pragma unroll 4
    for (int r = 0; r < 16; ++r) {
        float4 v = *(const float4*)(x + (size_t)(r0 + r) * INCH + c);
        s0 += v.x; s1 += v.y; s2 += v.z; s3 += v.w;
        q0 += v.x * v.x; q1 += v.y * v.y; q2 += v.z * v.z; q3 += v.w * v.w;
    }
    atomicAdd(&colsum[c + 0], s0); atomicAdd(&colsum[c + 1], s1);
    atomicAdd(&colsum[c + 2], s2); atomicAdd(&colsum[c + 3], s3);
    atomicAdd(&colsq[c + 0], q0); atomicAdd(&colsq[c + 1], q1);
    atomicAdd(&colsq[c + 2], q2); atomicAdd(&colsq[c + 3], q3);
}

// ---------- GraphNorm pass 2: per-column scale/shift ----------
// var = E[x^2] - g*(2-g)*mean^2 ; sc = rsqrt(var+eps)*w ; sh = b - g*mean*sc
__global__ void scale_k(const float* __restrict__ colsum, const float* __restrict__ colsq,
                        const float* __restrict__ gms, const float* __restrict__ gw,
                        const float* __restrict__ gb,
                        float* __restrict__ sc, float* __restrict__ sh) {
    int c = blockIdx.x * 256 + threadIdx.x;
    const float invn = 1.0f / NNODES;
    float m = colsum[c] * invn;
    float msq = colsq[c] * invn;
    float g = gms[c];
    float var = msq - g * (2.0f - g) * m * m;
    float s = rsqrtf(var + EPSV) * gw[c];
    sc[c] = s;
    sh[c] = gb[c] - g * m * s;
}

// ---------- GraphNorm pass 3: normalize + cast bf16 ----------
__global__ __launch_bounds__(256) void norm_k(const float* __restrict__ x,
                                              const float* __restrict__ sc,
                                              const float* __restrict__ sh,
                                              u16* __restrict__ xn) {
    int gid = blockIdx.x * 256 + threadIdx.x;
    int e = gid * 4;
    int c = e & (INCH - 1);
    float4 xv = *(const float4*)(x + e);
    float4 s4 = *(const float4*)(sc + c);
    float4 h4 = *(const float4*)(sh + c);
    ushort4 o;
    o.x = f2bf(xv.x * s4.x + h4.x);
    o.y = f2bf(xv.y * s4.y + h4.y);
    o.z = f2bf(xv.z * s4.z + h4.z);
    o.w = f2bf(xv.w * s4.w + h4.w);
    *(ushort4*)(xn + e) = o;
}

// ---------- weight convert: LDS-tiled transpose to [col][k] bf16 ----------
// 64x64 tiles: coalesced float4 reads, coalesced ushort4 writes.
__global__ __launch_bounds__(256) void wt1_k(const float* __restrict__ W, u16* __restrict__ Bt) {
    __shared__ u16 t[64][68];
    int k0 = blockIdx.y * 64, c0 = blockIdx.x * 64;
    int tc = (threadIdx.x & 15) * 4;
    int tk = threadIdx.x >> 4;
#pragma unroll
    for (int i = 0; i < 64; i += 16) {
        float4 v = *(const float4*)(W + (size_t)(k0 + tk + i) * HCH + c0 + tc);
        t[tc + 0][tk + i] = f2bf(v.x);
        t[tc + 1][tk + i] = f2bf(v.y);
        t[tc + 2][tk + i] = f2bf(v.z);
        t[tc + 3][tk + i] = f2bf(v.w);
    }
    __syncthreads();
    int wk = (threadIdx.x & 15) * 4;
    int wc = threadIdx.x >> 4;
#pragma unroll
    for (int i = 0; i < 64; i += 16) {
        ushort4 o;
        o.x = t[wc + i][wk + 0]; o.y = t[wc + i][wk + 1];
        o.z = t[wc + i][wk + 2]; o.w = t[wc + i][wk + 3];
        *(ushort4*)(Bt + (size_t)(c0 + wc + i) * 1024 + k0 + wk) = o;
    }
}

__global__ __launch_bounds__(256) void wt2_k(const float* __restrict__ Wm,
                                             const float* __restrict__ Ws,
                                             u16* __restrict__ Bt) {
    __shared__ u16 t[64][68];
    int k0 = blockIdx.y * 64, c0 = blockIdx.x * 64;
    const float* W = (c0 < OUTCH) ? Wm : Ws;
    int cb = (c0 < OUTCH) ? c0 : c0 - OUTCH;
    int tc = (threadIdx.x & 15) * 4;
    int tk = threadIdx.x >> 4;
#pragma unroll
    for (int i = 0; i < 64; i += 16) {
        float4 v = *(const float4*)(W + (size_t)(k0 + tk + i) * OUTCH + cb + tc);
        t[tc + 0][tk + i] = f2bf(v.x);
        t[tc + 1][tk + i] = f2bf(v.y);
        t[tc + 2][tk + i] = f2bf(v.z);
        t[tc + 3][tk + i] = f2bf(v.w);
    }
    __syncthreads();
    int wk = (threadIdx.x & 15) * 4;
    int wc = threadIdx.x >> 4;
#pragma unroll
    for (int i = 0; i < 64; i += 16) {
        ushort4 o;
        o.x = t[wc + i][wk + 0]; o.y = t[wc + i][wk + 1];
        o.z = t[wc + i][wk + 2]; o.w = t[wc + i][wk + 3];
        *(ushort4*)(Bt + (size_t)(c0 + wc + i) * 1024 + k0 + wk) = o;
    }
}

// ---------- CSR build ----------
__global__ void deg_k(const int* __restrict__ dst, int* __restrict__ cnt) {
    int e = blockIdx.x * 256 + threadIdx.x;
    if (e < NEDGES) atomicAdd(&cnt[dst[e]], 1);
}
__global__ void dis_k(const int* __restrict__ cnt, float* __restrict__ dis) {
    int i = blockIdx.x * 256 + threadIdx.x;
    if (i < NNODES) dis[i] = rsqrtf((float)(cnt[i] + 1));
}
__global__ void scan_k(const int* __restrict__ cnt, int* __restrict__ row_ptr,
                       int* __restrict__ cursor) {
    __shared__ int sm[256];
    int tid = threadIdx.x;
    const int per = 40;
    int base = tid * per;
    int s = 0;
    for (int i = 0; i < per; ++i) { int idx = base + i; if (idx < NNODES) s += cnt[idx]; }
    sm[tid] = s; __syncthreads();
    for (int off = 1; off < 256; off <<= 1) {
        int v = (tid >= off) ? sm[tid - off] : 0;
        __syncthreads();
        sm[tid] += v;
        __syncthreads();
    }
    int run = (tid == 0) ? 0 : sm[tid - 1];
    for (int i = 0; i < per; ++i) {
        int idx = base + i;
        if (idx < NNODES) { row_ptr[idx] = run; cursor[idx] = run; run += cnt[idx]; }
    }
    if (tid == 255) row_ptr[NNODES] = sm[255];
}
__global__ void fill_k(const int* __restrict__ src, const int* __restrict__ dst,
                       const float* __restrict__ dis, int* __restrict__ cursor,
                       int* __restrict__ csr_src, float* __restrict__ csr_w) {
    int e = blockIdx.x * 256 + threadIdx.x;
    if (e >= NEDGES) return;
    int s = src[e], d = dst[e];
    int pos = atomicAdd(&cursor[d], 1);
    csr_src[pos] = s;
    csr_w[pos] = dis[s] * dis[d];
}

// ---------- aggregation ----------
template<int MODE>   // MODE 1: +bias then leaky_relu
__global__ void agg_k(const u16* __restrict__ in, u16* __restrict__ out,
                      const int* __restrict__ row_ptr, const int* __restrict__ csr_src,
                      const float* __restrict__ csr_w, const float* __restrict__ dis,
                      const float* __restrict__ bias) {
    int node = blockIdx.x;
    int c = threadIdx.x * 4;
    float dv = dis[node];
    float selfw = dv * dv;
    ushort4 sv = *(const ushort4*)(in + (size_t)node * HCH + c);
    float a0 = bf2f(sv.x) * selfw, a1 = bf2f(sv.y) * selfw;
    float a2 = bf2f(sv.z) * selfw, a3 = bf2f(sv.w) * selfw;
    int e0 = row_ptr[node], e1 = row_ptr[node + 1];
    for (int e = e0; e < e1; ++e) {
        int s = csr_src[e];
        float w = csr_w[e];
        ushort4 v = *(const ushort4*)(in + (size_t)s * HCH + c);
        a0 += bf2f(v.x) * w; a1 += bf2f(v.y) * w;
        a2 += bf2f(v.z) * w; a3 += bf2f(v.w) * w;
    }
    if (MODE == 1) {
        float4 b = *(const float4*)(bias + c);
        a0 += b.x; a1 += b.y; a2 += b.z; a3 += b.w;
        a0 = a0 > 0.f ? a0 : NEG * a0;
        a1 = a1 > 0.f ? a1 : NEG * a1;
        a2 = a2 > 0.f ? a2 : NEG * a2;
        a3 = a3 > 0.f ? a3 : NEG * a3;
    }
    ushort4 o; o.x = f2bf(a0); o.y = f2bf(a1); o.z = f2bf(a2); o.w = f2bf(a3);
    *(ushort4*)(out + (size_t)node * HCH + c) = o;
}

// ---------- bf16 MFMA GEMM ----------
template<int EPI>
__global__ __launch_bounds__(256) void gemm_k(
    const u16* __restrict__ A, const u16* __restrict__ Bt,
    u16* __restrict__ Cbf, float* __restrict__ out,
    const float* __restrict__ bm, const float* __restrict__ bs) {
    __shared__ u16 As[128 * 32];
    __shared__ u16 Bs[128 * 32];
    const int tid = threadIdx.x;
    const int wave = tid >> 6;
    const int lane = tid & 63;
    const int row0 = blockIdx.y * 128;
    const int col0 = blockIdx.x * 128;
    const int wr = wave >> 1, wc = wave & 1;
    const int sr = lane >> 2;
    const int sc = (lane & 3) * 8;
    u16* AsW0 = &As[(wave * 16) * 32];
    u16* AsW1 = &As[(64 + wave * 16) * 32];
    u16* BsW0 = &Bs[(wave * 16) * 32];
    u16* BsW1 = &Bs[(64 + wave * 16) * 32];
    const u16* Ag0 = A + (size_t)(row0 + wave * 16 + sr) * 1024 + sc;
    const u16* Ag1 = A + (size_t)(row0 + 64 + wave * 16 + sr) * 1024 + sc;
    const u16* Bg0 = Bt + (size_t)(col0 + wave * 16 + sr) * 1024 + sc;
    const u16* Bg1 = Bt + (size_t)(col0 + 64 + wave * 16 + sr) * 1024 + sc;

    f32x4 acc[4][4] = {};
    const int arow = lane & 15;
    const int ak = (lane >> 4) * 8;
    for (int kk = 0; kk < 1024; kk += 32) {
        GL16(Ag0 + kk, AsW0);
        GL16(Ag1 + kk, AsW1);
        GL16(Bg0 + kk, BsW0);
        GL16(Bg1 + kk, BsW1);
        __syncthreads();
        bf16x8 af[4], bf[4];
#pragma unroll
        for (int m = 0; m < 4; ++m)
            af[m] = *reinterpret_cast<const bf16x8*>(&As[(wr * 64 + m * 16 + arow) * 32 + ak]);
#pragma unroll
        for (int n = 0; n < 4; ++n)
            bf[n] = *reinterpret_cast<const bf16x8*>(&Bs[(wc * 64 + n * 16 + arow) * 32 + ak]);
#pragma unroll
        for (int m = 0; m < 4; ++m)
#pragma unroll
            for (int n = 0; n < 4; ++n)
                acc[m][n] = __builtin_amdgcn_mfma_f32_16x16x32_bf16(af[m], bf[n], acc[m][n], 0, 0, 0);
        __syncthreads();
    }
    const int crow = (lane >> 4) * 4;
    const int ccol = lane & 15;
    if (EPI == 0) {
#pragma unroll
        for (int m = 0; m < 4; ++m) {
            int rbase = row0 + wr * 64 + m * 16 + crow;
#pragma unroll
            for (int n = 0; n < 4; ++n) {
                int col = col0 + wc * 64 + n * 16 + ccol;
                f32x4 v = acc[m][n];
#pragma unroll
                for (int r = 0; r < 4; ++r)
                    Cbf[(size_t)(rbase + r) * 1024 + col] = f2bf(v[r]);
            }
        }
    } else {
        const size_t NOUT = (size_t)NNODES * OUTCH;
#pragma unroll
        for (int n = 0; n < 4; ++n) {
            int col = col0 + wc * 64 + n * 16 + ccol;
            bool lo = col < OUTCH;
            int colo = lo ? col : col - OUTCH;
            float bias = lo ? bm[colo] : bs[colo];
#pragma unroll
            for (int m = 0; m < 4; ++m) {
                int rbase = row0 + wr * 64 + m * 16 + crow;
                f32x4 v = acc[m][n];
#pragma unroll
                for (int r = 0; r < 4; ++r) {
                    int rr = rbase + r;
                    if (rr < NNODES) {
                        float val = v[r] + bias;
                        if (lo) {
                            out[(size_t)rr * OUTCH + colo] = val;
                            out[NOUT + (size_t)rr * OUTCH + colo] = val;
                        } else {
                            out[2 * NOUT + (size_t)rr * OUTCH + colo] = val;
                        }
                    }
                }
            }
        }
    }
}

extern "C" void kernel_launch(void* const* d_in, const int* in_sizes, int n_in,
                              void* d_out, int out_size, void* d_ws, size_t ws_size,
                              hipStream_t stream) {
    const float* x   = (const float*)d_in[0];
    const int*   ei  = (const int*)d_in[1];
    const float* W1  = (const float*)d_in[2];
    const float* b1  = (const float*)d_in[3];
    const float* Wm  = (const float*)d_in[4];
    const float* bm  = (const float*)d_in[5];
    const float* Ws  = (const float*)d_in[6];
    const float* bs  = (const float*)d_in[7];
    const float* gw  = (const float*)d_in[8];
    const float* gb  = (const float*)d_in[9];
    const float* gms = (const float*)d_in[10];
    const int* srcI = ei;
    const int* dstI = ei + NEDGES;

    char* ws = (char*)d_ws;
    const size_t SBIG = (size_t)MPAD * 1024 * 2;
    u16* xn   = (u16*)(ws);
    u16* h1g  = (u16*)(ws + SBIG);
    u16* h    = (u16*)(ws + 2 * SBIG);
    u16* aggh = xn;
    u16* Bt1  = (u16*)(ws + 3 * SBIG);
    u16* Bt2  = (u16*)(ws + 3 * SBIG + (size_t)2 * 1024 * 1024);
    char* small   = ws + 3 * SBIG + (size_t)4 * 1024 * 1024;
    float* colsum = (float*)(small);
    float* colsq  = (float*)(small + 4096);
    int*   cnt    = (int*)(small + 8192);
    int*   row_ptr= (int*)(small + 49152);
    int*   cursor = (int*)(small + 49152 + 40960);
    float* dis    = (float*)(small + 49152 + 81920);
    int*   csr_src= (int*)(small + 49152 + 122880);
    float* csr_w  = (float*)(small + 49152 + 122880 + 640000);
    float* sc     = (float*)(small + 49152 + 122880 + 1280000);
    float* sh     = (float*)(small + 49152 + 122880 + 1280000 + 4096);

    // zero colsum | colsq | cnt (contiguous 48192 B)
    hipMemsetAsync(small, 0, 48192, stream);

    sumsq_k<<<625, 256, 0, stream>>>(x, colsum, colsq);
    scale_k<<<4, 256, 0, stream>>>(colsum, colsq, gms, gw, gb, sc, sh);
    norm_k<<<10000, 256, 0, stream>>>(x, sc, sh, xn);
    wt1_k<<<dim3(16, 16), 256, 0, stream>>>(W1, Bt1);
    wt2_k<<<dim3(16, 16), 256, 0, stream>>>(Wm, Ws, Bt2);
    deg_k<<<625, 256, 0, stream>>>(dstI, cnt);
    dis_k<<<40, 256, 0, stream>>>(cnt, dis);
    scan_k<<<1, 256, 0, stream>>>(cnt, row_ptr, cursor);
    fill_k<<<625, 256, 0, stream>>>(srcI, dstI, dis, cursor, csr_src, csr_w);

    gemm_k<0><<<dim3(8, 79), 256, 0, stream>>>(xn, Bt1, h1g, nullptr, nullptr, nullptr);
    agg_k<1><<<NNODES, 256, 0, stream>>>(h1g, h, row_ptr, csr_src, csr_w, dis, b1);
    agg_k<0><<<NNODES, 256, 0, stream>>>(h, aggh, row_ptr, csr_src, csr_w, dis, nullptr);
    gemm_k<1><<<dim3(8, 79), 256, 0, stream>>>(aggh, Bt2, nullptr, (float*)d_out, bm, bs);
}